// Round 2
// baseline (21206.355 us; speedup 1.0000x reference)
//
#include <hip/hip_runtime.h>

#define T_LEN 4096
#define E_DIM 1024
#define H_DIM 512
#define NT_DIM 32
#define NG 3072          // 2 * 3H columns of gi

typedef __attribute__((ext_vector_type(8))) short bf16x8;
typedef __attribute__((ext_vector_type(4))) float f32x4;
typedef unsigned long long ull;

__device__ inline unsigned short f2bf(float f) {
    unsigned int u = __float_as_uint(f);
    unsigned int r = (u + 0x7fffu + ((u >> 16) & 1u)) >> 16;
    return (unsigned short)r;
}
__device__ inline float bf2f(unsigned short u) {
    return __uint_as_float(((unsigned int)u) << 16);
}
__device__ inline ull packhs(float v, unsigned tag) {
    return (ull)__float_as_uint(v) | ((ull)tag << 32);
}

// ---------- kernel 1: embedding gather + bf16 cast  (xb[t][e]) ----------
__global__ void embed_cast(const int* __restrict__ sent, const float* __restrict__ emb,
                           unsigned short* __restrict__ xb) {
    int t = blockIdx.x;
    int row = sent[t];
    const float4* src = (const float4*)(emb + (size_t)row * E_DIM);
    ushort4* dst = (ushort4*)(xb + (size_t)t * E_DIM);
    float4 v = src[threadIdx.x];
    ushort4 o;
    o.x = f2bf(v.x); o.y = f2bf(v.y); o.z = f2bf(v.z); o.w = f2bf(v.w);
    dst[threadIdx.x] = o;
}

// ---------- kernel 2: W_ih (f then b) -> bf16, concat rows ----------
__global__ void wcast(const float* __restrict__ wf, const float* __restrict__ wb_,
                      unsigned short* __restrict__ w) {
    int r = blockIdx.x;  // 0..3071
    const float* src = (r < 1536) ? (wf + (size_t)r * E_DIM) : (wb_ + (size_t)(r - 1536) * E_DIM);
    const float4* s4 = (const float4*)src;
    ushort4* dst = (ushort4*)(w + (size_t)r * E_DIM);
    float4 v = s4[threadIdx.x];
    ushort4 o;
    o.x = f2bf(v.x); o.y = f2bf(v.y); o.z = f2bf(v.z); o.w = f2bf(v.w);
    dst[threadIdx.x] = o;
}

// ---------- kernel 3: gi = xb @ wb^T + b_ih   [4096 x 3072] -> bf16 ----------
#define LDST 40
__global__ __launch_bounds__(256) void gi_gemm(const unsigned short* __restrict__ xb,
                                               const unsigned short* __restrict__ wb,
                                               const float* __restrict__ bihf,
                                               const float* __restrict__ bihb,
                                               unsigned short* __restrict__ gi) {
    __shared__ __align__(16) unsigned short As[64 * LDST];
    __shared__ __align__(16) unsigned short Bs[64 * LDST];
    int tile_m = (blockIdx.x % 64) * 64;
    int tile_n = (blockIdx.x / 64) * 64;
    int tid = threadIdx.x;
    int lane = tid & 63, wv = tid >> 6;
    int quad = lane >> 4, r15 = lane & 15;
    int srow = tid >> 2, sseg = tid & 3;

    f32x4 acc[4] = {};
    for (int kb = 0; kb < E_DIM; kb += 32) {
        uint4 a = *(const uint4*)(xb + (size_t)(tile_m + srow) * E_DIM + kb + sseg * 8);
        uint4 b = *(const uint4*)(wb + (size_t)(tile_n + srow) * E_DIM + kb + sseg * 8);
        *(uint4*)&As[srow * LDST + sseg * 8] = a;
        *(uint4*)&Bs[srow * LDST + sseg * 8] = b;
        __syncthreads();
        bf16x8 af = *(bf16x8*)&As[(wv * 16 + r15) * LDST + quad * 8];
#pragma unroll
        for (int nt = 0; nt < 4; nt++) {
            bf16x8 bf = *(bf16x8*)&Bs[(nt * 16 + r15) * LDST + quad * 8];
            acc[nt] = __builtin_amdgcn_mfma_f32_16x16x32_bf16(af, bf, acc[nt], 0, 0, 0);
        }
        __syncthreads();
    }
#pragma unroll
    for (int nt = 0; nt < 4; nt++) {
        int gn = tile_n + nt * 16 + r15;
        float bias = (gn < 1536) ? bihf[gn] : bihb[gn - 1536];
#pragma unroll
        for (int rg = 0; rg < 4; rg++) {
            int gm = tile_m + wv * 16 + quad * 4 + rg;
            gi[(size_t)gm * NG + gn] = f2bf(acc[nt][rg] + bias);
        }
    }
}

// ---------- kernel 4: barrier-free persistent bidirectional GRU recurrence ----------
// 512 independent waves (256/dir), each owning TWO h-columns {c0, c0+1}.
// Per step, lane l polls its own k-slice h[8l..8l+8) of the previous row
// ({f32,tag} 8B self-validating slots, relaxed agent atomics) with a
// TWO-DEEP ping-pong (check batch A while batch B is in flight -> poll
// period ~L/2, expected detect ~ delta + 1.25 L instead of 1.5 L).
// Data arrives in exactly the lanes that consume it: 48 FMA/lane, full-wave
// shfl_xor butterfly (sums land in all lanes), lanes 0/1 do activations and
// store immediately. NO __syncthreads, NO LDS, no straggler wave.
__global__ __launch_bounds__(256, 1) void gru_rec(
    const float* __restrict__ whhf, const float* __restrict__ bhhf,
    const float* __restrict__ whhb, const float* __restrict__ bhhb,
    const unsigned short* __restrict__ gi, ull* __restrict__ hxf, ull* __restrict__ hxb) {
    int dir = blockIdx.x >> 6;                       // 0..63 fwd, 64..127 bwd
    int gw  = (blockIdx.x & 63) * 4 + (threadIdx.x >> 6);   // wave id 0..255
    int l   = threadIdx.x & 63;
    int c0  = gw * 2;                                // columns c0, c0+1
    const float* whh = dir ? whhb : whhf;
    const float* bhh = dir ? bhhb : bhhf;
    ull* hx = dir ? hxb : hxf;

    // persistent weights: lane l covers k in [8l, 8l+8) for both columns.
    // wA/wB index: [gate*2 + half], gates r,z,n at row offsets 0,512,1024.
    float4 wA[6], wB[6];
#pragma unroll
    for (int g3 = 0; g3 < 3; g3++) {
        const float4* pa = (const float4*)(whh + (size_t)(c0 + g3 * 512) * H_DIM + 8 * l);
        const float4* pb = (const float4*)(whh + (size_t)(c0 + 1 + g3 * 512) * H_DIM + 8 * l);
        wA[g3 * 2] = pa[0]; wA[g3 * 2 + 1] = pa[1];
        wB[g3 * 2] = pb[0]; wB[g3 * 2 + 1] = pb[1];
    }
    float bias_r = 0.f, bias_z = 0.f, bias_n = 0.f, h_own = 0.f;
    if (l < 2) {
        int c = c0 + l;
        bias_r = bhh[c]; bias_z = bhh[c + 512]; bias_n = bhh[c + 1024];
    }

    float h[8];
#pragma unroll
    for (int i = 0; i < 8; i++) h[i] = 0.f;          // h_{-1} = 0

    for (int s = 0; s < T_LEN; s++) {
        int row = dir ? (T_LEN - 1 - s) : s;
        // gi loads issued first — in flight during the poll, consumed in act
        float gir = 0.f, giz = 0.f, gin = 0.f;
        if (l < 2) {
            const unsigned short* gp = gi + (size_t)row * NG + dir * 1536 + (c0 + l);
            gir = bf2f(gp[0]); giz = bf2f(gp[512]); gin = bf2f(gp[1024]);
        }

        if (s > 0) {
            int prow = dir ? (T_LEN - s) : (s - 1);
            const ull* pp = hx + (size_t)prow * H_DIM + 8 * l;
            unsigned et = (unsigned)s;
            ull va[8], vb[8], gv[8];
#pragma unroll
            for (int i = 0; i < 8; i++)
                va[i] = __hip_atomic_load(pp + i, __ATOMIC_RELAXED, __HIP_MEMORY_SCOPE_AGENT);
#pragma unroll
            for (int i = 0; i < 8; i++)
                vb[i] = __hip_atomic_load(pp + i, __ATOMIC_RELAXED, __HIP_MEMORY_SCOPE_AGENT);
            for (;;) {
                bool ok = true;
#pragma unroll
                for (int i = 0; i < 8; i++) ok = ok && ((unsigned)(va[i] >> 32) == et);
                if (ok) {
#pragma unroll
                    for (int i = 0; i < 8; i++) gv[i] = va[i];
                    break;
                }
#pragma unroll
                for (int i = 0; i < 8; i++)
                    va[i] = __hip_atomic_load(pp + i, __ATOMIC_RELAXED, __HIP_MEMORY_SCOPE_AGENT);
                ok = true;
#pragma unroll
                for (int i = 0; i < 8; i++) ok = ok && ((unsigned)(vb[i] >> 32) == et);
                if (ok) {
#pragma unroll
                    for (int i = 0; i < 8; i++) gv[i] = vb[i];
                    break;
                }
#pragma unroll
                for (int i = 0; i < 8; i++)
                    vb[i] = __hip_atomic_load(pp + i, __ATOMIC_RELAXED, __HIP_MEMORY_SCOPE_AGENT);
            }
#pragma unroll
            for (int i = 0; i < 8; i++) h[i] = __uint_as_float((unsigned)gv[i]);
        }

        // per-lane partial dots over k in [8l, 8l+8) for both columns
        float prA, pzA, pnA, prB, pzB, pnB;
        prA = wA[0].x * h[0] + wA[0].y * h[1] + wA[0].z * h[2] + wA[0].w * h[3]
            + wA[1].x * h[4] + wA[1].y * h[5] + wA[1].z * h[6] + wA[1].w * h[7];
        pzA = wA[2].x * h[0] + wA[2].y * h[1] + wA[2].z * h[2] + wA[2].w * h[3]
            + wA[3].x * h[4] + wA[3].y * h[5] + wA[3].z * h[6] + wA[3].w * h[7];
        pnA = wA[4].x * h[0] + wA[4].y * h[1] + wA[4].z * h[2] + wA[4].w * h[3]
            + wA[5].x * h[4] + wA[5].y * h[5] + wA[5].z * h[6] + wA[5].w * h[7];
        prB = wB[0].x * h[0] + wB[0].y * h[1] + wB[0].z * h[2] + wB[0].w * h[3]
            + wB[1].x * h[4] + wB[1].y * h[5] + wB[1].z * h[6] + wB[1].w * h[7];
        pzB = wB[2].x * h[0] + wB[2].y * h[1] + wB[2].z * h[2] + wB[2].w * h[3]
            + wB[3].x * h[4] + wB[3].y * h[5] + wB[3].z * h[6] + wB[3].w * h[7];
        pnB = wB[4].x * h[0] + wB[4].y * h[1] + wB[4].z * h[2] + wB[4].w * h[3]
            + wB[5].x * h[4] + wB[5].y * h[5] + wB[5].z * h[6] + wB[5].w * h[7];

        // full-wave butterfly reduce (6 independent chains interleave)
#pragma unroll
        for (int m = 1; m < 64; m <<= 1) {
            prA += __shfl_xor(prA, m); pzA += __shfl_xor(pzA, m); pnA += __shfl_xor(pnA, m);
            prB += __shfl_xor(prB, m); pzB += __shfl_xor(pzB, m); pnB += __shfl_xor(pnB, m);
        }

        if (l < 2) {
            float pr = l ? prB : prA;
            float pz = l ? pzB : pzA;
            float pn = l ? pnB : pnA;
            float rr = 1.f / (1.f + __expf(-(gir + pr + bias_r)));
            float zz = 1.f / (1.f + __expf(-(giz + pz + bias_z)));
            float a = gin + rr * (pn + bias_n);
            a = fminf(20.f, fmaxf(-20.f, a));
            float e = __expf(-2.f * a);
            float nn = (1.f - e) / (1.f + e);
            float hnew = (1.f - zz) * nn + zz * h_own;
            h_own = hnew;
            __hip_atomic_store(hx + (size_t)row * H_DIM + c0 + l, packhs(hnew, (unsigned)(s + 1)),
                               __ATOMIC_RELAXED, __HIP_MEMORY_SCOPE_AGENT);
        }
    }
}

// ---------- kernel 5: out = [hf|hb] @ W_out^T   [4096 x 32] ----------
__global__ __launch_bounds__(256) void out_gemm(const ull* __restrict__ hxf,
                                                const ull* __restrict__ hxb,
                                                const float* __restrict__ wout,
                                                float* __restrict__ out) {
    __shared__ __align__(16) float ls[8][1028];
    int t0 = blockIdx.x * 8;
    int tid = threadIdx.x;
#pragma unroll
    for (int i = 0; i < 8; i++) {
        int col = tid * 4;   // 0..1020
        const ull* src = (col < 512) ? (hxf + (size_t)(t0 + i) * H_DIM + col)
                                     : (hxb + (size_t)(t0 + i) * H_DIM + (col - 512));
        ull s0 = src[0], s1 = src[1], s2 = src[2], s3 = src[3];
        ls[i][col + 0] = __uint_as_float((unsigned)s0);
        ls[i][col + 1] = __uint_as_float((unsigned)s1);
        ls[i][col + 2] = __uint_as_float((unsigned)s2);
        ls[i][col + 3] = __uint_as_float((unsigned)s3);
    }
    __syncthreads();
    int r8 = tid >> 5, gg = tid & 31;
    const float4* wp = (const float4*)(wout + (size_t)gg * 1024);
    float sum = 0.f;
#pragma unroll 8
    for (int j = 0; j < 256; j++) {
        float4 w = wp[j];
        float4 h = *(const float4*)&ls[r8][j * 4];
        sum += w.x * h.x + w.y * h.y + w.z * h.z + w.w * h.w;
    }
    out[(size_t)(t0 + r8) * NT_DIM + gg] = sum;
}

extern "C" void kernel_launch(void* const* d_in, const int* in_sizes, int n_in,
                              void* d_out, int out_size, void* d_ws, size_t ws_size,
                              hipStream_t stream) {
    const int*   sent = (const int*)d_in[0];
    const float* emb  = (const float*)d_in[1];
    const float* wihf = (const float*)d_in[2];
    const float* whhf = (const float*)d_in[3];
    const float* bihf = (const float*)d_in[4];
    const float* bhhf = (const float*)d_in[5];
    const float* wihb = (const float*)d_in[6];
    const float* whhb = (const float*)d_in[7];
    const float* bihb = (const float*)d_in[8];
    const float* bhhb = (const float*)d_in[9];
    const float* wout = (const float*)d_in[10];

    char* ws = (char*)d_ws;
    unsigned short* gi  = (unsigned short*)(ws);              // 4096*3072*2 = 25165824
    unsigned short* xb  = (unsigned short*)(ws + 25165824);   // 4096*1024*2 =  8388608
    unsigned short* wb  = (unsigned short*)(ws + 33554432);   // 3072*1024*2 =  6291456
    ull*            hxf = (ull*)(ws + 39845888);              // 4096*512*8  = 16777216
    ull*            hxb = (ull*)(ws + 56623104);              // 16777216 (total 73400320)
    float*          out = (float*)d_out;

    embed_cast<<<T_LEN, 256, 0, stream>>>(sent, emb, xb);
    wcast<<<NG, 256, 0, stream>>>(wihf, wihb, wb);
    gi_gemm<<<64 * 48, 256, 0, stream>>>(xb, wb, bihf, bihb, gi);
    gru_rec<<<128, 256, 0, stream>>>(whhf, bhhf, whhb, bhhb, gi, hxf, hxb);
    out_gemm<<<T_LEN / 8, 256, 0, stream>>>(hxf, hxb, wout, out);
}

// Round 3
// 7291.313 us; speedup vs baseline: 2.9084x; 2.9084x over previous
//
#include <hip/hip_runtime.h>

#define T_LEN 4096
#define E_DIM 1024
#define H_DIM 512
#define NT_DIM 32
#define NG 3072          // 2 * 3H columns of gi

typedef __attribute__((ext_vector_type(8))) short bf16x8;
typedef __attribute__((ext_vector_type(4))) float f32x4;
typedef __attribute__((ext_vector_type(4))) unsigned int u32x4;
typedef unsigned long long ull;

__device__ inline unsigned short f2bf(float f) {
    unsigned int u = __float_as_uint(f);
    unsigned int r = (u + 0x7fffu + ((u >> 16) & 1u)) >> 16;
    return (unsigned short)r;
}
__device__ inline float bf2f(unsigned short u) {
    return __uint_as_float(((unsigned int)u) << 16);
}
__device__ inline ull packhs(float v, unsigned tag) {
    return (ull)__float_as_uint(v) | ((ull)tag << 32);
}

// ---------- kernel 1: embedding gather + bf16 cast  (xb[t][e]) ----------
__global__ void embed_cast(const int* __restrict__ sent, const float* __restrict__ emb,
                           unsigned short* __restrict__ xb) {
    int t = blockIdx.x;
    int row = sent[t];
    const float4* src = (const float4*)(emb + (size_t)row * E_DIM);
    ushort4* dst = (ushort4*)(xb + (size_t)t * E_DIM);
    float4 v = src[threadIdx.x];
    ushort4 o;
    o.x = f2bf(v.x); o.y = f2bf(v.y); o.z = f2bf(v.z); o.w = f2bf(v.w);
    dst[threadIdx.x] = o;
}

// ---------- kernel 2: W_ih (f then b) -> bf16, concat rows ----------
__global__ void wcast(const float* __restrict__ wf, const float* __restrict__ wb_,
                      unsigned short* __restrict__ w) {
    int r = blockIdx.x;  // 0..3071
    const float* src = (r < 1536) ? (wf + (size_t)r * E_DIM) : (wb_ + (size_t)(r - 1536) * E_DIM);
    const float4* s4 = (const float4*)src;
    ushort4* dst = (ushort4*)(w + (size_t)r * E_DIM);
    float4 v = s4[threadIdx.x];
    ushort4 o;
    o.x = f2bf(v.x); o.y = f2bf(v.y); o.z = f2bf(v.z); o.w = f2bf(v.w);
    dst[threadIdx.x] = o;
}

// ---------- kernel 3: gi = xb @ wb^T + b_ih   [4096 x 3072] -> bf16 ----------
#define LDST 40
__global__ __launch_bounds__(256) void gi_gemm(const unsigned short* __restrict__ xb,
                                               const unsigned short* __restrict__ wb,
                                               const float* __restrict__ bihf,
                                               const float* __restrict__ bihb,
                                               unsigned short* __restrict__ gi) {
    __shared__ __align__(16) unsigned short As[64 * LDST];
    __shared__ __align__(16) unsigned short Bs[64 * LDST];
    int tile_m = (blockIdx.x % 64) * 64;
    int tile_n = (blockIdx.x / 64) * 64;
    int tid = threadIdx.x;
    int lane = tid & 63, wv = tid >> 6;
    int quad = lane >> 4, r15 = lane & 15;
    int srow = tid >> 2, sseg = tid & 3;

    f32x4 acc[4] = {};
    for (int kb = 0; kb < E_DIM; kb += 32) {
        uint4 a = *(const uint4*)(xb + (size_t)(tile_m + srow) * E_DIM + kb + sseg * 8);
        uint4 b = *(const uint4*)(wb + (size_t)(tile_n + srow) * E_DIM + kb + sseg * 8);
        *(uint4*)&As[srow * LDST + sseg * 8] = a;
        *(uint4*)&Bs[srow * LDST + sseg * 8] = b;
        __syncthreads();
        bf16x8 af = *(bf16x8*)&As[(wv * 16 + r15) * LDST + quad * 8];
#pragma unroll
        for (int nt = 0; nt < 4; nt++) {
            bf16x8 bf = *(bf16x8*)&Bs[(nt * 16 + r15) * LDST + quad * 8];
            acc[nt] = __builtin_amdgcn_mfma_f32_16x16x32_bf16(af, bf, acc[nt], 0, 0, 0);
        }
        __syncthreads();
    }
#pragma unroll
    for (int nt = 0; nt < 4; nt++) {
        int gn = tile_n + nt * 16 + r15;
        float bias = (gn < 1536) ? bihf[gn] : bihb[gn - 1536];
#pragma unroll
        for (int rg = 0; rg < 4; rg++) {
            int gm = tile_m + wv * 16 + quad * 4 + rg;
            gi[(size_t)gm * NG + gn] = f2bf(acc[nt][rg] + bias);
        }
    }
}

// ---------- kernel 4: persistent bidirectional GRU recurrence ----------
// 32 WGs x 512 threads: 16 per direction, 32 columns each.
// Contention-minimized h exchange: ONLY wave 0 polls, with 4x
// global_load_dwordx4 sc0 sc1 per lane (16B coherent loads; an aligned 8B
// {f32,tag} slot cannot tear within one 16B IF access). Request rate per
// poll iteration: 16 WG x 64 lane x 4 = 4K/dir vs 32K/dir in the 64-WG
// version — 8x fewer coherence-point requests.
// Compute: wave w owns cols g*32+w*4..+4; lane: kpart q=l&15 (32 k), col
// o=l>>4. 96 FMA/lane, reduce over q via shfl_xor 1/2/4/8 (intra-16).
// LDS h broadcast with pad idx(k)=k+4*(k>>5): reads 2-way (free).
__global__ __launch_bounds__(512, 2) void gru_rec(
    const float* __restrict__ whhf, const float* __restrict__ bhhf,
    const float* __restrict__ whhb, const float* __restrict__ bhhb,
    const unsigned short* __restrict__ gi, ull* __restrict__ hxf, ull* __restrict__ hxb) {
    int dir = blockIdx.x >> 4;
    int g   = blockIdx.x & 15;
    const float* whh = dir ? whhb : whhf;
    const float* bhh = dir ? bhhb : bhhf;
    ull* hx = dir ? hxb : hxf;

    int tid = threadIdx.x;
    int w = tid >> 6;        // wave 0..7
    int l = tid & 63;
    int q = l & 15;          // k-part: k in [32q, 32q+32)
    int o = l >> 4;          // col within wave's group of 4
    int c = g * 32 + w * 4 + o;   // column 0..511 (within direction)

    // persistent weights: 3 gates x 32 k = 24 float4 = 96 VGPRs
    float4 wr[8], wz[8], wn[8];
#pragma unroll
    for (int j = 0; j < 8; j++) {
        wr[j] = *(const float4*)(whh + (size_t)c * H_DIM + q * 32 + j * 4);
        wz[j] = *(const float4*)(whh + (size_t)(c + 512) * H_DIM + q * 32 + j * 4);
        wn[j] = *(const float4*)(whh + (size_t)(c + 1024) * H_DIM + q * 32 + j * 4);
    }
    bool owner = (q == 0);
    float bias_r = 0.f, bias_z = 0.f, bias_n = 0.f, h_own = 0.f;
    if (owner) { bias_r = bhh[c]; bias_z = bhh[c + 512]; bias_n = bhh[c + 1024]; }

    // padded LDS broadcast buffer: idx(k) = k + 4*(k>>5), 576 floats
    __shared__ float hsh[576];
    for (int i = tid; i < 576; i += 512) hsh[i] = 0.f;   // h_{-1} = 0
    __syncthreads();

    for (int s = 0; s < T_LEN; s++) {
        int row = dir ? (T_LEN - 1 - s) : s;
        // gi loads issued before the poll/barrier — in flight during the wait
        float gir = 0.f, giz = 0.f, gin = 0.f;
        if (owner) {
            const unsigned short* gp = gi + (size_t)row * NG + dir * 1536 + c;
            gir = bf2f(gp[0]); giz = bf2f(gp[512]); gin = bf2f(gp[1024]);
        }

        float hv[8];
        if (w == 0 && s > 0) {
            int prow = dir ? (T_LEN - s) : (s - 1);
            ull addr = (ull)(hx + (size_t)prow * H_DIM + 8 * l);
            unsigned et = (unsigned)s;
            u32x4 d0, d1, d2, d3;
            for (;;) {
                asm volatile("global_load_dwordx4 %0, %1, off sc0 sc1" : "=v"(d0) : "v"(addr));
                asm volatile("global_load_dwordx4 %0, %1, off offset:16 sc0 sc1" : "=v"(d1) : "v"(addr));
                asm volatile("global_load_dwordx4 %0, %1, off offset:32 sc0 sc1" : "=v"(d2) : "v"(addr));
                asm volatile("global_load_dwordx4 %0, %1, off offset:48 sc0 sc1" : "=v"(d3) : "v"(addr));
                asm volatile("s_waitcnt vmcnt(0)" ::: "memory");
                __builtin_amdgcn_sched_barrier(0);
                bool ok = (d0.y == et) & (d0.w == et) & (d1.y == et) & (d1.w == et)
                        & (d2.y == et) & (d2.w == et) & (d3.y == et) & (d3.w == et);
                if (ok) break;
            }
            hv[0] = __uint_as_float(d0.x); hv[1] = __uint_as_float(d0.z);
            hv[2] = __uint_as_float(d1.x); hv[3] = __uint_as_float(d1.z);
            hv[4] = __uint_as_float(d2.x); hv[5] = __uint_as_float(d2.z);
            hv[6] = __uint_as_float(d3.x); hv[7] = __uint_as_float(d3.z);
        }
        __syncthreads();   // barA: all waves done reading previous hsh
        if (w == 0 && s > 0) {
            int base = 8 * l + 4 * (l >> 2);   // idx(8l), contiguous 8 floats
            float4 va = { hv[0], hv[1], hv[2], hv[3] };
            float4 vb = { hv[4], hv[5], hv[6], hv[7] };
            *(float4*)&hsh[base]     = va;
            *(float4*)&hsh[base + 4] = vb;
        }
        __syncthreads();   // barB: hsh = h(s-1) ready

        float pr = 0.f, pz = 0.f, pn = 0.f;
        const float* hb = &hsh[36 * q];
#pragma unroll
        for (int j = 0; j < 8; j++) {
            float4 h4 = *(const float4*)(hb + 4 * j);
            pr += wr[j].x * h4.x + wr[j].y * h4.y + wr[j].z * h4.z + wr[j].w * h4.w;
            pz += wz[j].x * h4.x + wz[j].y * h4.y + wz[j].z * h4.z + wz[j].w * h4.w;
            pn += wn[j].x * h4.x + wn[j].y * h4.y + wn[j].z * h4.z + wn[j].w * h4.w;
        }
        // reduce over q (lane bits 0..3): intra-16 xor swaps
        pr += __shfl_xor(pr, 1); pz += __shfl_xor(pz, 1); pn += __shfl_xor(pn, 1);
        pr += __shfl_xor(pr, 2); pz += __shfl_xor(pz, 2); pn += __shfl_xor(pn, 2);
        pr += __shfl_xor(pr, 4); pz += __shfl_xor(pz, 4); pn += __shfl_xor(pn, 4);
        pr += __shfl_xor(pr, 8); pz += __shfl_xor(pz, 8); pn += __shfl_xor(pn, 8);

        if (owner) {
            float rr = 1.f / (1.f + __expf(-(gir + pr + bias_r)));
            float zz = 1.f / (1.f + __expf(-(giz + pz + bias_z)));
            float a = gin + rr * (pn + bias_n);
            a = fminf(20.f, fmaxf(-20.f, a));
            float e = __expf(-2.f * a);
            float nn = (1.f - e) / (1.f + e);
            float hnew = (1.f - zz) * nn + zz * h_own;
            h_own = hnew;
            __hip_atomic_store(hx + (size_t)row * H_DIM + c, packhs(hnew, (unsigned)(s + 1)),
                               __ATOMIC_RELAXED, __HIP_MEMORY_SCOPE_AGENT);
        }
    }
}

// ---------- kernel 5: out = [hf|hb] @ W_out^T   [4096 x 32] ----------
__global__ __launch_bounds__(256) void out_gemm(const ull* __restrict__ hxf,
                                                const ull* __restrict__ hxb,
                                                const float* __restrict__ wout,
                                                float* __restrict__ out) {
    __shared__ __align__(16) float ls[8][1028];
    int t0 = blockIdx.x * 8;
    int tid = threadIdx.x;
#pragma unroll
    for (int i = 0; i < 8; i++) {
        int col = tid * 4;   // 0..1020
        const ull* src = (col < 512) ? (hxf + (size_t)(t0 + i) * H_DIM + col)
                                     : (hxb + (size_t)(t0 + i) * H_DIM + (col - 512));
        ull s0 = src[0], s1 = src[1], s2 = src[2], s3 = src[3];
        ls[i][col + 0] = __uint_as_float((unsigned)s0);
        ls[i][col + 1] = __uint_as_float((unsigned)s1);
        ls[i][col + 2] = __uint_as_float((unsigned)s2);
        ls[i][col + 3] = __uint_as_float((unsigned)s3);
    }
    __syncthreads();
    int r8 = tid >> 5, gg = tid & 31;
    const float4* wp = (const float4*)(wout + (size_t)gg * 1024);
    float sum = 0.f;
#pragma unroll 8
    for (int j = 0; j < 256; j++) {
        float4 w = wp[j];
        float4 h = *(const float4*)&ls[r8][j * 4];
        sum += w.x * h.x + w.y * h.y + w.z * h.z + w.w * h.w;
    }
    out[(size_t)(t0 + r8) * NT_DIM + gg] = sum;
}

extern "C" void kernel_launch(void* const* d_in, const int* in_sizes, int n_in,
                              void* d_out, int out_size, void* d_ws, size_t ws_size,
                              hipStream_t stream) {
    const int*   sent = (const int*)d_in[0];
    const float* emb  = (const float*)d_in[1];
    const float* wihf = (const float*)d_in[2];
    const float* whhf = (const float*)d_in[3];
    const float* bihf = (const float*)d_in[4];
    const float* bhhf = (const float*)d_in[5];
    const float* wihb = (const float*)d_in[6];
    const float* whhb = (const float*)d_in[7];
    const float* bihb = (const float*)d_in[8];
    const float* bhhb = (const float*)d_in[9];
    const float* wout = (const float*)d_in[10];

    char* ws = (char*)d_ws;
    unsigned short* gi  = (unsigned short*)(ws);              // 4096*3072*2 = 25165824
    unsigned short* xb  = (unsigned short*)(ws + 25165824);   // 4096*1024*2 =  8388608
    unsigned short* wb  = (unsigned short*)(ws + 33554432);   // 3072*1024*2 =  6291456
    ull*            hxf = (ull*)(ws + 39845888);              // 4096*512*8  = 16777216
    ull*            hxb = (ull*)(ws + 56623104);              // 16777216 (total 73400320)
    float*          out = (float*)d_out;

    embed_cast<<<T_LEN, 256, 0, stream>>>(sent, emb, xb);
    wcast<<<NG, 256, 0, stream>>>(wihf, wihb, wb);
    gi_gemm<<<64 * 48, 256, 0, stream>>>(xb, wb, bihf, bihb, gi);
    gru_rec<<<32, 512, 0, stream>>>(whhf, bhhf, whhb, bhhb, gi, hxf, hxb);
    out_gemm<<<T_LEN / 8, 256, 0, stream>>>(hxf, hxb, wout, out);
}